// Round 3
// baseline (28236.130 us; speedup 1.0000x reference)
//
#include <hip/hip_runtime.h>
#include <hip/hip_cooperative_groups.h>
#include <math.h>

namespace cg = cooperative_groups;

#define VV 32000
#define EE 512
#define HH 512
#define BB 16
#define TT 128
#define SS 128
#define XD 1024
#define NPB 250
#define BH (BB*HH)

__device__ __forceinline__ float sigf(float x){ return 1.0f/(1.0f+expf(-x)); }

__device__ __forceinline__ float fget(const float4& v, int d){
    return d==0 ? v.x : d==1 ? v.y : d==2 ? v.z : v.w;
}

// lv layout: stride 20, stagger in {0,4} (fits the 4-float pad; no wrap, so
// rows can never alias: max(stagger)+15 = 19 < 20). float4-aligned.
__device__ __forceinline__ int lvoff(int row){ return row * 20 + (((row >> 2) & 1) << 2); }

// ---- block-wide reductions (512 threads = 8 waves), trailing sync so smem reusable ----
__device__ __forceinline__ float bredmax(float v, float* s8, int tid){
    #pragma unroll
    for (int o = 32; o >= 1; o >>= 1) v = fmaxf(v, __shfl_xor(v, o));
    if ((tid & 63) == 0) s8[tid >> 6] = v;
    __syncthreads();
    float r = fmaxf(fmaxf(fmaxf(s8[0],s8[1]),fmaxf(s8[2],s8[3])),
                    fmaxf(fmaxf(s8[4],s8[5]),fmaxf(s8[6],s8[7])));
    __syncthreads();
    return r;
}
__device__ __forceinline__ float bredsum(float v, float* s8, int tid){
    #pragma unroll
    for (int o = 32; o >= 1; o >>= 1) v += __shfl_xor(v, o);
    if ((tid & 63) == 0) s8[tid >> 6] = v;
    __syncthreads();
    float r = ((s8[0]+s8[1])+(s8[2]+s8[3]))+((s8[4]+s8[5])+(s8[6]+s8[7]));
    __syncthreads();
    return r;
}
__device__ __forceinline__ void bredamax(float& v, int& idx, float* s8, int* si8, int tid){
    #pragma unroll
    for (int o = 32; o >= 1; o >>= 1){
        float ov = __shfl_xor(v, o); int oi = __shfl_xor(idx, o);
        if (ov > v || (ov == v && oi < idx)) { v = ov; idx = oi; }
    }
    if ((tid & 63) == 0) { s8[tid >> 6] = v; si8[tid >> 6] = idx; }
    __syncthreads();
    float bv = s8[0]; int bi = si8[0];
    #pragma unroll
    for (int w = 1; w < 8; ++w){
        float ov = s8[w]; int oi = si8[w];
        if (ov > bv || (ov == bv && oi < bi)) { bv = ov; bi = oi; }
    }
    __syncthreads();
    v = bv; idx = bi;
}

// ---- one LSTM cell step: block owns 2 h-indices (8 gate rows), all 16 batches ----
template<int XLEN>
__device__ __forceinline__ void lstm_cell(
    int tid, int j0,
    const float* __restrict__ wih, const float* __restrict__ whh,
    const float* __restrict__ bih, const float* __restrict__ bhh,
    const float* __restrict__ xsrc,
    const float* __restrict__ hold, const float* __restrict__ cold,
    float* __restrict__ hnew, float* __restrict__ cnew)
{
    const int bb = tid >> 5, h32 = tid & 31;
    constexpr int KX = XLEN >> 5;   // 32 (layer0) or 16 (layer1)
    constexpr int KH = 16;          // 512/32
    float acc[8];
    #pragma unroll
    for (int r = 0; r < 8; ++r) acc[r] = 0.f;
    const float* xb = xsrc + bb * XLEN + h32 * KX;
    const float* hb = hold + (bb << 9) + h32 * KH;
    const float* wx[8]; const float* wh[8];
    #pragma unroll
    for (int r = 0; r < 8; ++r) {
        const int row = (r >> 1) * HH + j0 + (r & 1);   // gate=(r>>1), jj=(r&1)
        wx[r] = wih + (long)row * XLEN + h32 * KX;
        wh[r] = whh + ((long)row << 9) + h32 * KH;
    }
    #pragma unroll
    for (int i = 0; i < KX; i += 4) {
        float4 xv = *(const float4*)(xb + i);
        #pragma unroll
        for (int r = 0; r < 8; ++r) {
            float4 wv = *(const float4*)(wx[r] + i);
            acc[r] = fmaf(wv.w, xv.w, fmaf(wv.z, xv.z, fmaf(wv.y, xv.y, fmaf(wv.x, xv.x, acc[r]))));
        }
    }
    #pragma unroll
    for (int i = 0; i < KH; i += 4) {
        float4 xv = *(const float4*)(hb + i);
        #pragma unroll
        for (int r = 0; r < 8; ++r) {
            float4 wv = *(const float4*)(wh[r] + i);
            acc[r] = fmaf(wv.w, xv.w, fmaf(wv.z, xv.z, fmaf(wv.y, xv.y, fmaf(wv.x, xv.x, acc[r]))));
        }
    }
    #pragma unroll
    for (int o = 16; o >= 1; o >>= 1) {
        #pragma unroll
        for (int r = 0; r < 8; ++r) acc[r] += __shfl_xor(acc[r], o);
    }
    if (h32 == 0) {
        #pragma unroll
        for (int jj = 0; jj < 2; ++jj) {
            const int j = j0 + jj;
            const float gi = acc[0 + jj] + bih[j]          + bhh[j];
            const float gf = acc[2 + jj] + bih[HH + j]     + bhh[HH + j];
            const float gg = acc[4 + jj] + bih[2*HH + j]   + bhh[2*HH + j];
            const float go = acc[6 + jj] + bih[3*HH + j]   + bhh[3*HH + j];
            const float cp = cold[(bb << 9) + j];
            const float cn = sigf(gf) * cp + sigf(gi) * tanhf(gg);
            const float hn = sigf(go) * tanhf(cn);
            hnew[(bb << 9) + j] = hn;
            cnew[(bb << 9) + j] = cn;
        }
    }
}

// ---- attention scores for next step: scores[b,s] = dot(h1[b], enc[s,b,:]) ----
__device__ __forceinline__ void calc_scores(int blk, int tid,
    const float* __restrict__ h1, const float* __restrict__ enc, float* __restrict__ scores)
{
    const int idx = (blk - NPB) * 512 + tid;
    if (idx >= BB * SS) return;
    const int s = idx >> 4, b = idx & 15;
    const float* ep = enc + ((long)s * BB + b) * HH;
    const float* hp = h1 + b * HH;
    float a0 = 0.f, a1 = 0.f, a2 = 0.f, a3 = 0.f;
    #pragma unroll 2
    for (int k = 0; k < HH; k += 16) {
        float4 e0 = *(const float4*)(ep + k),      hv0 = *(const float4*)(hp + k);
        float4 e1 = *(const float4*)(ep + k + 4),  hv1 = *(const float4*)(hp + k + 4);
        float4 e2 = *(const float4*)(ep + k + 8),  hv2 = *(const float4*)(hp + k + 8);
        float4 e3 = *(const float4*)(ep + k + 12), hv3 = *(const float4*)(hp + k + 12);
        a0 += e0.x*hv0.x + e0.y*hv0.y + e0.z*hv0.z + e0.w*hv0.w;
        a1 += e1.x*hv1.x + e1.y*hv1.y + e1.z*hv1.z + e1.w*hv1.w;
        a2 += e2.x*hv2.x + e2.y*hv2.y + e2.z*hv2.z + e2.w*hv2.w;
        a3 += e3.x*hv3.x + e3.y*hv3.y + e3.z*hv3.z + e3.w*hv3.w;
    }
    scores[b * SS + s] = (a0 + a1) + (a2 + a3);
}

// ---- projection tile: 128 vocab rows/block, logits + softmax/argmax partials ----
__device__ __forceinline__ void proj_tile(
    int blk, int tid, const float* __restrict__ h1,
    const float* __restrict__ ow, const float* __restrict__ ob,
    float* __restrict__ rawt, long rstride,
    float* __restrict__ pm, float* __restrict__ psm, int* __restrict__ pid,
    float* __restrict__ h1t, float* __restrict__ lv)
{
    // stage h1 [k][b] staggered (stagger monotone in k -> collision-free)
    for (int i = tid; i < BB * HH; i += 512) {
        const int b = i >> 9, k = i & 511;
        h1t[k * 20 + ((k >> 5) << 2) + b] = h1[i];
    }
    __syncthreads();

    const int q = tid >> 4, h = tid & 15;   // q: 4-row group, h: k-sixteenth
    const int v0 = blk * 128 + q * 4;
    const int k0 = h << 5;
    float a[64];
    #pragma unroll
    for (int i = 0; i < 64; ++i) a[i] = 0.f;

    const float* w0 = ow + (long)v0 * HH + k0;
    #pragma unroll 2
    for (int kk = 0; kk < 32; kk += 4) {
        float4 wv0 = *(const float4*)(w0 + kk);
        float4 wv1 = *(const float4*)(w0 + HH + kk);
        float4 wv2 = *(const float4*)(w0 + 2 * HH + kk);
        float4 wv3 = *(const float4*)(w0 + 3 * HH + kk);
        #pragma unroll
        for (int d = 0; d < 4; ++d) {
            const int kd = k0 + kk + d;
            const float* hp = h1t + kd * 20 + ((kd >> 5) << 2);
            float4 hv0 = *(const float4*)(hp);
            float4 hv1 = *(const float4*)(hp + 4);
            float4 hv2 = *(const float4*)(hp + 8);
            float4 hv3 = *(const float4*)(hp + 12);
            const float hv[16] = {hv0.x,hv0.y,hv0.z,hv0.w, hv1.x,hv1.y,hv1.z,hv1.w,
                                  hv2.x,hv2.y,hv2.z,hv2.w, hv3.x,hv3.y,hv3.z,hv3.w};
            const float wr[4] = { fget(wv0,d), fget(wv1,d), fget(wv2,d), fget(wv3,d) };
            #pragma unroll
            for (int r = 0; r < 4; ++r)
                #pragma unroll
                for (int j = 0; j < 16; ++j)
                    a[r*16+j] = fmaf(wr[r], hv[j], a[r*16+j]);
        }
    }

    // reduce-scatter over the 16-lane k-group: 60 shuffles, each lane ends with 4 finals
#define RS_ROUND(O, NH)                                                  \
    {                                                                    \
        const bool up = (h & (O)) != 0;                                  \
        _Pragma("unroll")                                                \
        for (int i = 0; i < (NH); ++i) {                                 \
            float lo = a[i], hi = a[i + (NH)];                           \
            float snd = up ? lo : hi;                                    \
            float rcv = __shfl_xor(snd, (O));                            \
            a[i] = (up ? hi : lo) + rcv;                                 \
        }                                                                \
    }
    RS_ROUND(1, 32)
    RS_ROUND(2, 16)
    RS_ROUND(4, 8)
    RS_ROUND(8, 4)
#undef RS_ROUND
    // lane h holds global value indices g = 4*bitrev4(h) + {0..3}; g = r*16 + j
    const int br = ((h & 1) << 3) | ((h & 2) << 1) | ((h & 4) >> 1) | ((h & 8) >> 3);
    const int rr = br >> 2;
    const int jb = (br & 3) << 2;
    {
        const int row = q * 4 + rr;
        const float bv = ob[v0 + rr];
        float* dst = lv + lvoff(row) + jb;
        float4 val = { a[0] + bv, a[1] + bv, a[2] + bv, a[3] + bv };
        *(float4*)dst = val;
    }
    __syncthreads();

    // coalesced raw-logit store (plain store: read back next phase from L2)
    for (int i = tid; i < 128 * BB; i += 512) {
        const int b = i >> 7, row = i & 127;
        rawt[(long)b * rstride + blk * 128 + row] = lv[lvoff(row) + b];
    }

    // per-(block,b) partials: max / first-argmax / sum(exp(x-max))
    const int b2 = tid >> 5, l = tid & 31;
    float vals[4]; float m = -INFINITY; int mi = 0;
    #pragma unroll
    for (int r = 0; r < 4; ++r) {
        const int row = l * 4 + r;
        const float x = lv[lvoff(row) + b2];
        vals[r] = x;
        if (x > m) { m = x; mi = row; }
    }
    #pragma unroll
    for (int o = 16; o >= 1; o >>= 1) {
        float om = __shfl_xor(m, o); int oi = __shfl_xor(mi, o);
        if (om > m || (om == m && oi < mi)) { m = om; mi = oi; }
    }
    float z = 0.f;
    #pragma unroll
    for (int r = 0; r < 4; ++r) z += expf(vals[r] - m);
    #pragma unroll
    for (int o = 16; o >= 1; o >>= 1) z += __shfl_xor(z, o);
    if (l == 0) {
        pm[blk * BB + b2] = m;
        psm[blk * BB + b2] = z;
        pid[blk * BB + b2] = blk * 128 + mi;
    }
}

struct Params {
    const float *emb, *h0i, *c0i, *enc;
    const float *wih0, *whh0, *bih0, *bhh0;
    const float *wih1, *whh1, *bih1, *bhh1;
    const float *ow, *ob;
    float *out, *seqo, *attn;
    float *st, *xbuf, *scores, *pm, *psm;
    int *pid;
    float *lraw;
    int usews;
};

__global__ __launch_bounds__(512, 2) void k_decode(Params p)
{
    cg::grid_group grid = cg::this_grid();
    const int blk = blockIdx.x;
    const int tid = threadIdx.x;

    __shared__ float smem[12896];
    float* h1t = smem;            // proj phase: 10304
    float* lv  = smem + 10304;    // proj phase: 2560 (stride-20, stagger {0,4})
    float* aw  = smem;            // phase A alias: 128
    float* s8  = smem + 160;      // 8
    int*   si8 = (int*)(smem + 176);  // 8

    // prologue: scores for step 0 from initial top-layer hidden state
    if (blk >= NPB) calc_scores(blk, tid, p.h0i + BH, p.enc, p.scores);
    grid.sync();

    for (int t = 0; t <= TT; ++t) {
        // ---------------- phase A ----------------
        if (blk < BB) {
            const int b = blk;
            int tok = 1;
            if (t > 0) {
                float m = -INFINITY; int mi = 0x7fffffff;
                if (tid < NPB) { m = p.pm[tid * BB + b]; mi = p.pid[tid * BB + b]; }
                bredamax(m, mi, s8, si8, tid);
                tok = mi;
                if (tid == 0) p.seqo[b * TT + (t - 1)] = (float)tok;
            }
            if (t < TT) {
                float sc = (tid < SS) ? p.scores[b * SS + tid] : -INFINITY;
                float M = bredmax(sc, s8, tid);
                float e = (tid < SS) ? expf(sc - M) : 0.f;
                float Z = bredsum(e, s8, tid);
                float av = e / Z;
                if (tid < SS) {
                    aw[tid] = av;
                    __builtin_nontemporal_store(av, p.attn + ((long)b * TT + t) * SS + tid);
                }
                __syncthreads();
                float cacc = 0.f;
                const float* ep = p.enc + b * HH + tid;
                #pragma unroll 8
                for (int s = 0; s < SS; ++s)
                    cacc = fmaf(aw[s], ep[(long)s * BH], cacc);
                p.xbuf[b * XD + EE + tid] = cacc;
                p.xbuf[b * XD + tid] = p.emb[(long)tok * EE + tid];
            }
        } else if (t > 0) {
            // logp writers: 240 blocks, 15 per batch
            const int wb = blk - BB;
            const int b = wb / 15, c = wb - b * 15;
            float m = (tid < NPB) ? p.pm[tid * BB + b] : -INFINITY;
            m = bredmax(m, s8, tid);
            float z = (tid < NPB) ? p.psm[tid * BB + b] * expf(p.pm[tid * BB + b] - m) : 0.f;
            z = bredsum(z, s8, tid);
            const float lse = m + logf(z);
            const long obase = ((long)b * TT + (t - 1)) * (long)VV;
            const float* rb = p.usews ? (p.lraw + (long)b * VV) : (p.out + obase);
            float* obp = p.out + obase;
            const int v0 = c * 2134, v1 = min(v0 + 2134, VV);
            for (int v = v0 + tid; v < v1; v += 512)
                __builtin_nontemporal_store(__builtin_nontemporal_load(rb + v) - lse, obp + v);
        }
        if (t == TT) return;
        grid.sync();

        // state ping-pong
        const int po = t & 1, pn = (t + 1) & 1;
        const float* h0o = t ? p.st + (po * 4 + 0) * BH : p.h0i;
        const float* c0o = t ? p.st + (po * 4 + 1) * BH : p.c0i;
        const float* h1o = t ? p.st + (po * 4 + 2) * BH : p.h0i + BH;
        const float* c1o = t ? p.st + (po * 4 + 3) * BH : p.c0i + BH;
        float* h0n = p.st + (pn * 4 + 0) * BH;
        float* c0n = p.st + (pn * 4 + 1) * BH;
        float* h1n = p.st + (pn * 4 + 2) * BH;
        float* c1n = p.st + (pn * 4 + 3) * BH;

        // ---------------- phase B: LSTM layer 0 ----------------
        lstm_cell<XD>(tid, blk * 2, p.wih0, p.whh0, p.bih0, p.bhh0, p.xbuf, h0o, c0o, h0n, c0n);
        grid.sync();

        // ---------------- phase C: LSTM layer 1 ----------------
        lstm_cell<HH>(tid, blk * 2, p.wih1, p.whh1, p.bih1, p.bhh1, h0n, h1o, c1o, h1n, c1n);
        grid.sync();

        // ---------------- phase D: vocab projection + next scores ----------------
        {
            float* rawt = p.usews ? p.lraw : p.out + (long)t * VV;
            const long rstride = p.usews ? (long)VV : (long)TT * (long)VV;
            if (blk < NPB)
                proj_tile(blk, tid, h1n, p.ow, p.ob, rawt, rstride, p.pm, p.psm, p.pid, h1t, lv);
            else
                calc_scores(blk, tid, h1n, p.enc, p.scores);
        }
        grid.sync();
    }
}

extern "C" void kernel_launch(void* const* d_in, const int* in_sizes, int n_in,
                              void* d_out, int out_size, void* d_ws, size_t ws_size,
                              hipStream_t stream)
{
    (void)in_sizes; (void)n_in; (void)out_size;
    Params p;
    p.emb  = (const float*)d_in[0];
    p.h0i  = (const float*)d_in[1];
    p.c0i  = (const float*)d_in[2];
    p.enc  = (const float*)d_in[3];
    p.wih0 = (const float*)d_in[4];
    p.whh0 = (const float*)d_in[5];
    p.bih0 = (const float*)d_in[6];
    p.bhh0 = (const float*)d_in[7];
    p.wih1 = (const float*)d_in[8];
    p.whh1 = (const float*)d_in[9];
    p.bih1 = (const float*)d_in[10];
    p.bhh1 = (const float*)d_in[11];
    p.ow   = (const float*)d_in[12];
    p.ob   = (const float*)d_in[13];

    float* out = (float*)d_out;
    p.out  = out;
    p.seqo = out + (long)BB * TT * VV;
    p.attn = p.seqo + (long)BB * TT;

    float* ws = (float*)d_ws;
    p.st     = ws;                       // 2 x {h0,c0,h1,c1} x B*H
    p.xbuf   = p.st + 8 * BH;            // B x XD
    p.scores = p.xbuf + BB * XD;         // B x S
    p.pm     = p.scores + BB * SS;       // NPB x B
    p.psm    = p.pm + NPB * BB;
    p.pid    = (int*)(p.psm + NPB * BB);
    p.lraw   = (float*)(p.pid + NPB * BB);   // B x V
    const size_t need = (size_t)((char*)(p.lraw + (long)BB * VV) - (char*)ws);
    p.usews = (ws_size >= need) ? 1 : 0;

    void* args[] = { &p };
    hipLaunchCooperativeKernel((void*)k_decode, dim3(256), dim3(512), args, 0, stream);
}